// Round 1
// baseline (680.836 us; speedup 1.0000x reference)
//
#include <hip/hip_runtime.h>
#include <stdint.h>

typedef short bf16x8 __attribute__((ext_vector_type(8)));
typedef unsigned short us8 __attribute__((ext_vector_type(8)));
typedef float f32x4 __attribute__((ext_vector_type(4)));
typedef unsigned short u16;
typedef unsigned int u32;

#define LDK 40   // padded LDS row stride (bf16 elems): 80B -> 2-way bank alias only

__device__ __forceinline__ u16 f2bf(float f) {
    u32 u = __float_as_uint(f);
    u32 r = (u + 0x7FFFu + ((u >> 16) & 1u)) >> 16;   // RNE
    return (u16)r;
}
__device__ __forceinline__ float bf2f(u16 h) {
    return __uint_as_float(((u32)h) << 16);
}

// stage a 128x32 f32 tile (row stride rs floats) into hi/lo bf16 LDS [128][LDK]
__device__ __forceinline__ void stage_tile(const float* __restrict__ src, int64_t rs,
                                           u16* __restrict__ Lh, u16* __restrict__ Ll,
                                           int tid) {
    const int row = tid >> 1;
    const int c0 = (tid & 1) << 4;
    const float4* p = reinterpret_cast<const float4*>(src + (int64_t)row * rs + c0);
    float4 a = p[0], b = p[1], c = p[2], d = p[3];
    float v[16] = {a.x,a.y,a.z,a.w, b.x,b.y,b.z,b.w, c.x,c.y,c.z,c.w, d.x,d.y,d.z,d.w};
    us8 h0, h1, l0, l1;
#pragma unroll
    for (int j = 0; j < 8; ++j) {
        u16 hh = f2bf(v[j]);      h0[j] = hh; l0[j] = f2bf(v[j]     - bf2f(hh));
        u16 hg = f2bf(v[8 + j]);  h1[j] = hg; l1[j] = f2bf(v[8 + j] - bf2f(hg));
    }
    us8* dh = reinterpret_cast<us8*>(&Lh[row * LDK + c0]);
    us8* dl = reinterpret_cast<us8*>(&Ll[row * LDK + c0]);
    dh[0] = h0; dh[1] = h1;
    dl[0] = l0; dl[1] = l1;
}

// one BK=32 step: 16 fragment pairs x 3 split-combos (hi*hi + hi*lo + lo*hi)
__device__ __forceinline__ void mfma_step3(const u16* Ah, const u16* Al,
                                           const u16* Bh, const u16* Bl,
                                           int wrow, int wcol, int lane,
                                           f32x4 acc[4][4]) {
    const int rl = lane & 15;
    const int k8 = (lane >> 4) << 3;
    bf16x8 ah[4], al[4], bh[4], bl[4];
#pragma unroll
    for (int i = 0; i < 4; ++i) {
        const int ra = (wrow + i * 16 + rl) * LDK + k8;
        const int rb = (wcol + i * 16 + rl) * LDK + k8;
        ah[i] = *reinterpret_cast<const bf16x8*>(&Ah[ra]);
        al[i] = *reinterpret_cast<const bf16x8*>(&Al[ra]);
        bh[i] = *reinterpret_cast<const bf16x8*>(&Bh[rb]);
        bl[i] = *reinterpret_cast<const bf16x8*>(&Bl[rb]);
    }
#pragma unroll
    for (int m = 0; m < 4; ++m)
#pragma unroll
        for (int n = 0; n < 4; ++n) {
            f32x4 c = acc[m][n];
            c = __builtin_amdgcn_mfma_f32_16x16x32_bf16(ah[m], bh[n], c, 0, 0, 0);
            c = __builtin_amdgcn_mfma_f32_16x16x32_bf16(ah[m], bl[n], c, 0, 0, 0);
            c = __builtin_amdgcn_mfma_f32_16x16x32_bf16(al[m], bh[n], c, 0, 0, 0);
            acc[m][n] = c;
        }
}

template<int KSTEPS>
__device__ __forceinline__ void gemm_core(const float* __restrict__ Abase, int64_t Ars,
                                          const float* __restrict__ Bbase, int64_t Brs,
                                          u16* Ah, u16* Al, u16* Bh, u16* Bl,
                                          int tid, f32x4 acc[4][4]) {
    const int lane = tid & 63;
    const int w = tid >> 6;
    const int wrow = (w >> 1) << 6;
    const int wcol = (w & 1) << 6;
    for (int kb = 0; kb < KSTEPS; ++kb) {
        stage_tile(Abase + kb * 32, Ars, Ah, Al, tid);
        stage_tile(Bbase + kb * 32, Brs, Bh, Bl, tid);
        __syncthreads();
        mfma_step3(Ah, Al, Bh, Bl, wrow, wcol, lane, acc);
        __syncthreads();
    }
}

// ---------------- K1: qkv = xc @ w_qkv^T   [8192,1024]x[3072,1024]^T -> [8192,3072]
__global__ __launch_bounds__(256, 2) void k1_qkv(const float* __restrict__ x,
                                                 const float* __restrict__ ctx,
                                                 const float* __restrict__ wqkv,
                                                 float* __restrict__ qkv) {
    __shared__ u16 Ah[128 * LDK], Al[128 * LDK], Bh[128 * LDK], Bl[128 * LDK];
    const int tid = threadIdx.x;
    const int n0 = blockIdx.x << 7;          // 0..2944
    const int m0 = blockIdx.y << 7;          // 0..8064
    const int b = m0 >> 11;
    const int s0 = m0 & 2047;
    const float* Abase = (s0 < 1024)
        ? (x   + ((int64_t)b * 1024 + s0)          * 1024)
        : (ctx + ((int64_t)b * 1024 + (s0 - 1024)) * 1024);
    const float* Bbase = wqkv + (int64_t)n0 * 1024;
    f32x4 acc[4][4] = {};
    gemm_core<32>(Abase, 1024, Bbase, 1024, Ah, Al, Bh, Bl, tid, acc);
    const int lane = tid & 63;
    const int w = tid >> 6;
    const int wrow = (w >> 1) << 6, wcol = (w & 1) << 6;
    const int r4 = (lane >> 4) << 2, cc = lane & 15;
#pragma unroll
    for (int m = 0; m < 4; ++m)
#pragma unroll
        for (int n = 0; n < 4; ++n)
#pragma unroll
            for (int j = 0; j < 4; ++j)
                qkv[(int64_t)(m0 + wrow + m * 16 + r4 + j) * 3072
                    + (n0 + wcol + n * 16 + cc)] = acc[m][n][j];
}

// ---------------- K2: S = scale * Q K^T per (b,h)  -> attn region of d_out (pre-softmax)
__global__ __launch_bounds__(256, 2) void k2_qkt(const float* __restrict__ qkv,
                                                 float* __restrict__ S) {
    __shared__ u16 Ah[128 * LDK], Al[128 * LDK], Bh[128 * LDK], Bl[128 * LDK];
    const int tid = threadIdx.x;
    const int z = blockIdx.z, b = z >> 4, h = z & 15;
    const int n0 = blockIdx.x << 7, m0 = blockIdx.y << 7;
    // Q[i,e] = qkv[row 2i][h*128+e]
    const float* Abase = qkv + ((int64_t)b * 2048 + 2 * m0) * 3072 + h * 128;
    // K[j,e] = qkv[row 2j+pk][c0k+e]
    const int pk  = (h < 8) ? 0 : 1;
    const int c0k = (h < 8) ? (2048 + h * 128) : ((h - 8) * 128);
    const float* Bbase = qkv + ((int64_t)b * 2048 + 2 * n0 + pk) * 3072 + c0k;
    f32x4 acc[4][4] = {};
    gemm_core<4>(Abase, 6144, Bbase, 6144, Ah, Al, Bh, Bl, tid, acc);
    float* Sout = S + ((int64_t)z << 20);
    const int lane = tid & 63;
    const int w = tid >> 6;
    const int wrow = (w >> 1) << 6, wcol = (w & 1) << 6;
    const int r4 = (lane >> 4) << 2, cc = lane & 15;
#pragma unroll
    for (int m = 0; m < 4; ++m)
#pragma unroll
        for (int n = 0; n < 4; ++n)
#pragma unroll
            for (int j = 0; j < 4; ++j)
                Sout[(int64_t)(m0 + wrow + m * 16 + r4 + j) * 1024
                     + (n0 + wcol + n * 16 + cc)] = acc[m][n][j] * 0.125f;
}

// ---------------- K3: softmax rows of S (in-place -> final attn) + O = P V, scatter to o_r
__global__ __launch_bounds__(256, 2) void k3_smpv(const float* __restrict__ qkv,
                                                  float* __restrict__ S,
                                                  float* __restrict__ orr) {
    __shared__ u16 Ph[128 * LDK], Pl[128 * LDK], Vh[128 * LDK], Vl[128 * LDK];
    __shared__ float red[256];
    __shared__ float rowM[128], rowInv[128];
    const int tid = threadIdx.x;
    const int z = blockIdx.y, b = z >> 4, h = z & 15;
    const int m0 = blockIdx.x << 7;
    float* Sbase = S + ((int64_t)z << 20) + (int64_t)m0 * 1024;
    const int q = tid >> 1, hf = tid & 1;
    const float4* sp4 = reinterpret_cast<const float4*>(Sbase + (int64_t)q * 1024 + (hf << 9));
    { // sweep 1: row max (each thread: half a row = 512 elems)
        float m = -3.0e38f;
        for (int i = 0; i < 128; ++i) {
            float4 v = sp4[i];
            m = fmaxf(m, fmaxf(fmaxf(v.x, v.y), fmaxf(v.z, v.w)));
        }
        red[tid] = m;
    }
    __syncthreads();
    if (tid < 128) rowM[tid] = fmaxf(red[2 * tid], red[2 * tid + 1]);
    __syncthreads();
    { // sweep 2: sum exp(v - M)
        const float M = rowM[q];
        float s = 0.f;
        for (int i = 0; i < 128; ++i) {
            float4 v = sp4[i];
            s += __expf(v.x - M) + __expf(v.y - M) + __expf(v.z - M) + __expf(v.w - M);
        }
        red[tid] = s;
    }
    __syncthreads();
    if (tid < 128) rowInv[tid] = 1.0f / (red[2 * tid] + red[2 * tid + 1]);
    __syncthreads();
    // V[kpos,e] = qkv[row 2*kpos+1][c0v+e]
    const int c0v = (h < 8) ? (1024 + h * 128) : (2048 + (h - 8) * 128);
    const float* Vbase = qkv + ((int64_t)b * 2048 + 1) * 3072 + c0v;
    const int lane = tid & 63;
    const int w = tid >> 6;
    const int wrow = (w >> 1) << 6, wcol = (w & 1) << 6;
    f32x4 acc[4][4] = {};
    for (int kb = 0; kb < 32; ++kb) {
        { // stage P: read S chunk, normalize, write attn back to global, hi/lo to LDS
            const int c0 = (tid & 1) << 4;
            float* sp = Sbase + (int64_t)q * 1024 + kb * 32 + c0;
            const float M = rowM[q], inv = rowInv[q];
            float4 a = ((const float4*)sp)[0], bb = ((const float4*)sp)[1];
            float4 c = ((const float4*)sp)[2], d = ((const float4*)sp)[3];
            float v[16] = {a.x,a.y,a.z,a.w, bb.x,bb.y,bb.z,bb.w,
                           c.x,c.y,c.z,c.w, d.x,d.y,d.z,d.w};
            float p[16];
#pragma unroll
            for (int j = 0; j < 16; ++j) p[j] = __expf(v[j] - M) * inv;
            ((float4*)sp)[0] = make_float4(p[0],  p[1],  p[2],  p[3]);
            ((float4*)sp)[1] = make_float4(p[4],  p[5],  p[6],  p[7]);
            ((float4*)sp)[2] = make_float4(p[8],  p[9],  p[10], p[11]);
            ((float4*)sp)[3] = make_float4(p[12], p[13], p[14], p[15]);
            us8 h0, h1, l0, l1;
#pragma unroll
            for (int j = 0; j < 8; ++j) {
                u16 hh = f2bf(p[j]);      h0[j] = hh; l0[j] = f2bf(p[j]     - bf2f(hh));
                u16 hg = f2bf(p[8 + j]);  h1[j] = hg; l1[j] = f2bf(p[8 + j] - bf2f(hg));
            }
            us8* dh = reinterpret_cast<us8*>(&Ph[q * LDK + c0]);
            us8* dl = reinterpret_cast<us8*>(&Pl[q * LDK + c0]);
            dh[0] = h0; dh[1] = h1;
            dl[0] = l0; dl[1] = l1;
        }
        { // stage V transposed: LDS Vh[e][kk]
            const int kk = tid & 31;
            const int e0 = (tid >> 5) << 4;
            const float* vp = Vbase + (int64_t)(kb * 32 + kk) * 6144 + e0;
            float4 a = ((const float4*)vp)[0], bb = ((const float4*)vp)[1];
            float4 c = ((const float4*)vp)[2], d = ((const float4*)vp)[3];
            float v[16] = {a.x,a.y,a.z,a.w, bb.x,bb.y,bb.z,bb.w,
                           c.x,c.y,c.z,c.w, d.x,d.y,d.z,d.w};
#pragma unroll
            for (int j = 0; j < 16; ++j) {
                u16 hh = f2bf(v[j]);
                Vh[(e0 + j) * LDK + kk] = hh;
                Vl[(e0 + j) * LDK + kk] = f2bf(v[j] - bf2f(hh));
            }
        }
        __syncthreads();
        mfma_step3(Ph, Pl, Vh, Vl, wrow, wcol, lane, acc);
        __syncthreads();
    }
    // scatter O[i,e] -> o_r[b, 2i+(h>>3), (h&7)*128+e]
    const int r4 = (lane >> 4) << 2, cc = lane & 15;
    const int po = h >> 3, cb = (h & 7) << 7;
#pragma unroll
    for (int m = 0; m < 4; ++m)
#pragma unroll
        for (int n = 0; n < 4; ++n)
#pragma unroll
            for (int j = 0; j < 4; ++j) {
                const int qrow = m0 + wrow + m * 16 + r4 + j;
                orr[((int64_t)b * 2048 + 2 * qrow + po) * 1024
                    + cb + wcol + n * 16 + cc] = acc[m][n][j];
            }
}

// ---------------- K4: out = o_r @ w_proj^T + b_proj   [8192,1024]x[1024,1024]^T
__global__ __launch_bounds__(256, 2) void k4_out(const float* __restrict__ orr,
                                                 const float* __restrict__ wproj,
                                                 const float* __restrict__ bias,
                                                 float* __restrict__ out) {
    __shared__ u16 Ah[128 * LDK], Al[128 * LDK], Bh[128 * LDK], Bl[128 * LDK];
    const int tid = threadIdx.x;
    const int n0 = blockIdx.x << 7, m0 = blockIdx.y << 7;
    const float* Abase = orr + (int64_t)m0 * 1024;
    const float* Bbase = wproj + (int64_t)n0 * 1024;
    f32x4 acc[4][4] = {};
    gemm_core<32>(Abase, 1024, Bbase, 1024, Ah, Al, Bh, Bl, tid, acc);
    const int lane = tid & 63;
    const int w = tid >> 6;
    const int wrow = (w >> 1) << 6, wcol = (w & 1) << 6;
    const int r4 = (lane >> 4) << 2, cc = lane & 15;
#pragma unroll
    for (int m = 0; m < 4; ++m)
#pragma unroll
        for (int n = 0; n < 4; ++n)
#pragma unroll
            for (int j = 0; j < 4; ++j)
                out[(int64_t)(m0 + wrow + m * 16 + r4 + j) * 1024
                    + (n0 + wcol + n * 16 + cc)]
                    = acc[m][n][j] + bias[n0 + wcol + n * 16 + cc];
}

extern "C" void kernel_launch(void* const* d_in, const int* in_sizes, int n_in,
                              void* d_out, int out_size, void* d_ws, size_t ws_size,
                              hipStream_t stream) {
    const float* x     = (const float*)d_in[0];
    const float* ctx   = (const float*)d_in[1];
    const float* wqkv  = (const float*)d_in[2];
    const float* wproj = (const float*)d_in[3];
    const float* bias  = (const float*)d_in[4];
    float* out  = (float*)d_out;                 // [4,2048,1024]
    float* attn = out + 8388608;                 // [4,16,1024,1024]
    float* qkv  = (float*)d_ws;                  // [8192,3072] f32 = 100.7 MB
    float* orr  = qkv + 25165824;                // [8192,1024] f32 = 33.6 MB (128 MiB total ws)

    k1_qkv <<<dim3(24, 64),    256, 0, stream>>>(x, ctx, wqkv, qkv);
    k2_qkt <<<dim3(8, 8, 64),  256, 0, stream>>>(qkv, attn);
    k3_smpv<<<dim3(8, 64),     256, 0, stream>>>(qkv, attn, orr);
    k4_out <<<dim3(8, 64),     256, 0, stream>>>(orr, wproj, bias, out);
}

// Round 2
// 601.228 us; speedup vs baseline: 1.1324x; 1.1324x over previous
//
#include <hip/hip_runtime.h>
#include <stdint.h>

typedef short bf16x8 __attribute__((ext_vector_type(8)));
typedef unsigned short us8 __attribute__((ext_vector_type(8)));
typedef float f32x4 __attribute__((ext_vector_type(4)));
typedef unsigned short u16;
typedef unsigned int u32;

#define LDK 40   // padded LDS row stride (bf16 elems): 80B -> 2-way bank alias only

__device__ __forceinline__ u16 f2bf(float f) {
    u32 u = __float_as_uint(f);
    u32 r = (u + 0x7FFFu + ((u >> 16) & 1u)) >> 16;   // RNE
    return (u16)r;
}
__device__ __forceinline__ float bf2f(u16 h) {
    return __uint_as_float(((u32)h) << 16);
}

// stage a 128x32 f32 tile (row stride rs floats) into hi/lo bf16 LDS [128][LDK]
__device__ __forceinline__ void stage_tile(const float* __restrict__ src, int64_t rs,
                                           u16* __restrict__ Lh, u16* __restrict__ Ll,
                                           int tid) {
    const int row = tid >> 1;
    const int c0 = (tid & 1) << 4;
    const float4* p = reinterpret_cast<const float4*>(src + (int64_t)row * rs + c0);
    float4 a = p[0], b = p[1], c = p[2], d = p[3];
    float v[16] = {a.x,a.y,a.z,a.w, b.x,b.y,b.z,b.w, c.x,c.y,c.z,c.w, d.x,d.y,d.z,d.w};
    us8 h0, h1, l0, l1;
#pragma unroll
    for (int j = 0; j < 8; ++j) {
        u16 hh = f2bf(v[j]);      h0[j] = hh; l0[j] = f2bf(v[j]     - bf2f(hh));
        u16 hg = f2bf(v[8 + j]);  h1[j] = hg; l1[j] = f2bf(v[8 + j] - bf2f(hg));
    }
    us8* dh = reinterpret_cast<us8*>(&Lh[row * LDK + c0]);
    us8* dl = reinterpret_cast<us8*>(&Ll[row * LDK + c0]);
    dh[0] = h0; dh[1] = h1;
    dl[0] = l0; dl[1] = l1;
}

// one BK=32 step: 16 fragment pairs x 3 split-combos (hi*hi + hi*lo + lo*hi)
__device__ __forceinline__ void mfma_step3(const u16* Ah, const u16* Al,
                                           const u16* Bh, const u16* Bl,
                                           int wrow, int wcol, int lane,
                                           f32x4 acc[4][4]) {
    const int rl = lane & 15;
    const int k8 = (lane >> 4) << 3;
    bf16x8 ah[4], al[4], bh[4], bl[4];
#pragma unroll
    for (int i = 0; i < 4; ++i) {
        const int ra = (wrow + i * 16 + rl) * LDK + k8;
        const int rb = (wcol + i * 16 + rl) * LDK + k8;
        ah[i] = *reinterpret_cast<const bf16x8*>(&Ah[ra]);
        al[i] = *reinterpret_cast<const bf16x8*>(&Al[ra]);
        bh[i] = *reinterpret_cast<const bf16x8*>(&Bh[rb]);
        bl[i] = *reinterpret_cast<const bf16x8*>(&Bl[rb]);
    }
#pragma unroll
    for (int m = 0; m < 4; ++m)
#pragma unroll
        for (int n = 0; n < 4; ++n) {
            f32x4 c = acc[m][n];
            c = __builtin_amdgcn_mfma_f32_16x16x32_bf16(ah[m], bh[n], c, 0, 0, 0);
            c = __builtin_amdgcn_mfma_f32_16x16x32_bf16(ah[m], bl[n], c, 0, 0, 0);
            c = __builtin_amdgcn_mfma_f32_16x16x32_bf16(al[m], bh[n], c, 0, 0, 0);
            acc[m][n] = c;
        }
}

template<int KSTEPS>
__device__ __forceinline__ void gemm_core(const float* __restrict__ Abase, int64_t Ars,
                                          const float* __restrict__ Bbase, int64_t Brs,
                                          u16* Ah, u16* Al, u16* Bh, u16* Bl,
                                          int tid, f32x4 acc[4][4]) {
    const int lane = tid & 63;
    const int w = tid >> 6;
    const int wrow = (w >> 1) << 6;
    const int wcol = (w & 1) << 6;
    for (int kb = 0; kb < KSTEPS; ++kb) {
        stage_tile(Abase + kb * 32, Ars, Ah, Al, tid);
        stage_tile(Bbase + kb * 32, Brs, Bh, Bl, tid);
        __syncthreads();
        mfma_step3(Ah, Al, Bh, Bl, wrow, wcol, lane, acc);
        __syncthreads();
    }
}

// ---------------- K1: qkv = xc @ w_qkv^T   [8192,1024]x[3072,1024]^T -> [8192,3072]
__global__ __launch_bounds__(256, 2) void k1_qkv(const float* __restrict__ x,
                                                 const float* __restrict__ ctx,
                                                 const float* __restrict__ wqkv,
                                                 float* __restrict__ qkv) {
    __shared__ u16 Ah[128 * LDK], Al[128 * LDK], Bh[128 * LDK], Bl[128 * LDK];
    const int tid = threadIdx.x;
    const int n0 = blockIdx.x << 7;          // 0..2944
    const int m0 = blockIdx.y << 7;          // 0..8064
    const int b = m0 >> 11;
    const int s0 = m0 & 2047;
    const float* Abase = (s0 < 1024)
        ? (x   + ((int64_t)b * 1024 + s0)          * 1024)
        : (ctx + ((int64_t)b * 1024 + (s0 - 1024)) * 1024);
    const float* Bbase = wqkv + (int64_t)n0 * 1024;
    f32x4 acc[4][4] = {};
    gemm_core<32>(Abase, 1024, Bbase, 1024, Ah, Al, Bh, Bl, tid, acc);
    const int lane = tid & 63;
    const int w = tid >> 6;
    const int wrow = (w >> 1) << 6, wcol = (w & 1) << 6;
    const int r4 = (lane >> 4) << 2, cc = lane & 15;
#pragma unroll
    for (int m = 0; m < 4; ++m)
#pragma unroll
        for (int n = 0; n < 4; ++n)
#pragma unroll
            for (int j = 0; j < 4; ++j)
                qkv[(int64_t)(m0 + wrow + m * 16 + r4 + j) * 3072
                    + (n0 + wcol + n * 16 + cc)] = acc[m][n][j];
}

// ---------------- K2: S = scale * Q K^T per (b,h) -> attn region (pre-softmax)
//                  + per-tile row stats (max, sumexp) -> statsM/statsL
__global__ __launch_bounds__(256, 2) void k2_qkt(const float* __restrict__ qkv,
                                                 float* __restrict__ S,
                                                 float* __restrict__ statsM,
                                                 float* __restrict__ statsL) {
    __shared__ u16 Ah[128 * LDK], Al[128 * LDK], Bh[128 * LDK], Bl[128 * LDK];
    __shared__ float pM[4][64], pL[4][64], rowMx[128];
    const int tid = threadIdx.x;
    const int z = blockIdx.z, b = z >> 4, h = z & 15;
    const int n0 = blockIdx.x << 7, m0 = blockIdx.y << 7;
    // Q[i,e] = qkv[row 2i][h*128+e]
    const float* Abase = qkv + ((int64_t)b * 2048 + 2 * m0) * 3072 + h * 128;
    // K[j,e] = qkv[row 2j+pk][c0k+e]
    const int pk  = (h < 8) ? 0 : 1;
    const int c0k = (h < 8) ? (2048 + h * 128) : ((h - 8) * 128);
    const float* Bbase = qkv + ((int64_t)b * 2048 + 2 * n0 + pk) * 3072 + c0k;
    f32x4 acc[4][4] = {};
    gemm_core<4>(Abase, 6144, Bbase, 6144, Ah, Al, Bh, Bl, tid, acc);
    float* Sout = S + ((int64_t)z << 20);
    const int lane = tid & 63;
    const int w = tid >> 6;
    const int wrow = (w >> 1) << 6, wcol = (w & 1) << 6;
    const int r4 = (lane >> 4) << 2, cc = lane & 15;
#pragma unroll
    for (int m = 0; m < 4; ++m)
#pragma unroll
        for (int n = 0; n < 4; ++n)
#pragma unroll
            for (int j = 0; j < 4; ++j)
                Sout[(int64_t)(m0 + wrow + m * 16 + r4 + j) * 1024
                     + (n0 + wcol + n * 16 + cc)] = acc[m][n][j] * 0.125f;
    // ---- tile row stats (on UNscaled acc; scale folded into exp / final M)
    const int g = lane >> 4, rl = lane & 15;
#pragma unroll
    for (int m = 0; m < 4; ++m)
#pragma unroll
        for (int j = 0; j < 4; ++j) {
            float t = fmaxf(fmaxf(acc[m][0][j], acc[m][1][j]),
                            fmaxf(acc[m][2][j], acc[m][3][j]));
            t = fmaxf(t, __shfl_xor(t, 1));
            t = fmaxf(t, __shfl_xor(t, 2));
            t = fmaxf(t, __shfl_xor(t, 4));
            t = fmaxf(t, __shfl_xor(t, 8));
            if (rl == 0) pM[w][m * 16 + g * 4 + j] = t;
        }
    __syncthreads();
    if (tid < 128) {
        const int rh = tid >> 6;
        rowMx[tid] = fmaxf(pM[rh * 2][tid & 63], pM[rh * 2 + 1][tid & 63]);
    }
    __syncthreads();
#pragma unroll
    for (int m = 0; m < 4; ++m)
#pragma unroll
        for (int j = 0; j < 4; ++j) {
            const float M = rowMx[wrow + m * 16 + g * 4 + j];
            float s = 0.f;
#pragma unroll
            for (int n = 0; n < 4; ++n)
                s += __expf((acc[m][n][j] - M) * 0.125f);
            s += __shfl_xor(s, 1);
            s += __shfl_xor(s, 2);
            s += __shfl_xor(s, 4);
            s += __shfl_xor(s, 8);
            if (rl == 0) pL[w][m * 16 + g * 4 + j] = s;
        }
    __syncthreads();
    if (tid < 128) {
        const int rh = tid >> 6;
        const float l = pL[rh * 2][tid & 63] + pL[rh * 2 + 1][tid & 63];
        const int64_t idx = ((int64_t)(z * 8 + blockIdx.x) << 10) + m0 + tid;
        statsM[idx] = rowMx[tid] * 0.125f;
        statsL[idx] = l;
    }
}

// ---------------- K3: normalize S -> attn (single read) + O = P V, scatter to o_r
__global__ __launch_bounds__(256, 4) void k3_smpv(const float* __restrict__ qkv,
                                                  float* __restrict__ S,
                                                  const float* __restrict__ statsM,
                                                  const float* __restrict__ statsL,
                                                  float* __restrict__ orr) {
    __shared__ u16 Ph[64 * LDK], Vh[128 * LDK];
    __shared__ float rowM[64], rowInv[64];
    const int tid = threadIdx.x;
    const int z = blockIdx.y, b = z >> 4, h = z & 15;
    const int m0 = blockIdx.x << 6;          // 64 q-rows per block
    if (tid < 64) {
        const int rr = m0 + tid;
        float Mt[8], Lt[8];
        float M = -3.0e38f;
#pragma unroll
        for (int t = 0; t < 8; ++t) {
            Mt[t] = statsM[((int64_t)(z * 8 + t) << 10) + rr];
            Lt[t] = statsL[((int64_t)(z * 8 + t) << 10) + rr];
            M = fmaxf(M, Mt[t]);
        }
        float l = 0.f;
#pragma unroll
        for (int t = 0; t < 8; ++t) l += Lt[t] * __expf(Mt[t] - M);
        rowM[tid] = M;
        rowInv[tid] = 1.0f / l;
    }
    __syncthreads();
    float* Sbase = S + ((int64_t)z << 20) + (int64_t)m0 * 1024;
    const int c0v = (h < 8) ? (1024 + h * 128) : (2048 + (h - 8) * 128);
    const float* Vbase = qkv + ((int64_t)b * 2048 + 1) * 3072 + c0v;
    const int lane = tid & 63, w = tid >> 6;
    const int wrow = (w >> 1) << 5, wcol = (w & 1) << 6;   // wave tile 32q x 64e
    // P role: 4 threads per row, 8 cols each
    const int q = tid >> 2, c0 = (tid & 3) << 3;
    float* sp_base = Sbase + (int64_t)q * 1024 + c0;
    const float M = rowM[q], inv = rowInv[q];
    // V role: 32 k x 16 e per thread-group
    const int kk = tid & 31, e0 = (tid >> 5) << 4;
    f32x4 acc[2][4] = {};
    float4 ca = reinterpret_cast<const float4*>(sp_base)[0];
    float4 cb = reinterpret_cast<const float4*>(sp_base)[1];
    for (int kb = 0; kb < 32; ++kb) {
        float4 na, nb;
        if (kb < 31) {   // prefetch next S chunk (issued before this iter's stores)
            na = reinterpret_cast<const float4*>(sp_base + (kb + 1) * 32)[0];
            nb = reinterpret_cast<const float4*>(sp_base + (kb + 1) * 32)[1];
        }
        { // stage V (hi only), transposed: Vh[e][kk]
            const float* vp = Vbase + (int64_t)(kb * 32 + kk) * 6144 + e0;
            float4 v0 = ((const float4*)vp)[0], v1 = ((const float4*)vp)[1];
            float4 v2 = ((const float4*)vp)[2], v3 = ((const float4*)vp)[3];
            float vv[16] = {v0.x,v0.y,v0.z,v0.w, v1.x,v1.y,v1.z,v1.w,
                            v2.x,v2.y,v2.z,v2.w, v3.x,v3.y,v3.z,v3.w};
#pragma unroll
            for (int j = 0; j < 16; ++j)
                Vh[(e0 + j) * LDK + kk] = f2bf(vv[j]);
        }
        { // normalize P, write final attn, stage Ph (hi only)
            float p[8] = {ca.x,ca.y,ca.z,ca.w, cb.x,cb.y,cb.z,cb.w};
            us8 hh;
#pragma unroll
            for (int j = 0; j < 8; ++j) {
                const float e = __expf(p[j] - M) * inv;
                p[j] = e;
                hh[j] = f2bf(e);
            }
            float4* st = reinterpret_cast<float4*>(sp_base + kb * 32);
            st[0] = make_float4(p[0], p[1], p[2], p[3]);
            st[1] = make_float4(p[4], p[5], p[6], p[7]);
            *reinterpret_cast<us8*>(&Ph[q * LDK + c0]) = hh;
        }
        __syncthreads();
        { // PV mfma, hi-only
            const int rl = lane & 15, k8 = (lane >> 4) << 3;
            bf16x8 a[2], bv[4];
#pragma unroll
            for (int i = 0; i < 2; ++i)
                a[i] = *reinterpret_cast<const bf16x8*>(&Ph[(wrow + i * 16 + rl) * LDK + k8]);
#pragma unroll
            for (int i = 0; i < 4; ++i)
                bv[i] = *reinterpret_cast<const bf16x8*>(&Vh[(wcol + i * 16 + rl) * LDK + k8]);
#pragma unroll
            for (int m = 0; m < 2; ++m)
#pragma unroll
                for (int n = 0; n < 4; ++n)
                    acc[m][n] = __builtin_amdgcn_mfma_f32_16x16x32_bf16(a[m], bv[n], acc[m][n], 0, 0, 0);
        }
        __syncthreads();
        if (kb < 31) { ca = na; cb = nb; }
    }
    // scatter O[i,e] -> o_r[b, 2i+(h>>3), (h&7)*128+e]
    const int r4 = (lane >> 4) << 2, cc = lane & 15;
    const int po = h >> 3, cb2 = (h & 7) << 7;
#pragma unroll
    for (int m = 0; m < 2; ++m)
#pragma unroll
        for (int n = 0; n < 4; ++n)
#pragma unroll
            for (int j = 0; j < 4; ++j) {
                const int qrow = m0 + wrow + m * 16 + r4 + j;
                orr[((int64_t)b * 2048 + 2 * qrow + po) * 1024
                    + cb2 + wcol + n * 16 + cc] = acc[m][n][j];
            }
}

// ---------------- K4: out = o_r @ w_proj^T + b_proj   [8192,1024]x[1024,1024]^T
__global__ __launch_bounds__(256, 2) void k4_out(const float* __restrict__ orr,
                                                 const float* __restrict__ wproj,
                                                 const float* __restrict__ bias,
                                                 float* __restrict__ out) {
    __shared__ u16 Ah[128 * LDK], Al[128 * LDK], Bh[128 * LDK], Bl[128 * LDK];
    const int tid = threadIdx.x;
    const int n0 = blockIdx.x << 7, m0 = blockIdx.y << 7;
    const float* Abase = orr + (int64_t)m0 * 1024;
    const float* Bbase = wproj + (int64_t)n0 * 1024;
    f32x4 acc[4][4] = {};
    gemm_core<32>(Abase, 1024, Bbase, 1024, Ah, Al, Bh, Bl, tid, acc);
    const int lane = tid & 63;
    const int w = tid >> 6;
    const int wrow = (w >> 1) << 6, wcol = (w & 1) << 6;
    const int r4 = (lane >> 4) << 2, cc = lane & 15;
#pragma unroll
    for (int m = 0; m < 4; ++m)
#pragma unroll
        for (int n = 0; n < 4; ++n)
#pragma unroll
            for (int j = 0; j < 4; ++j)
                out[(int64_t)(m0 + wrow + m * 16 + r4 + j) * 1024
                    + (n0 + wcol + n * 16 + cc)]
                    = acc[m][n][j] + bias[n0 + wcol + n * 16 + cc];
}

extern "C" void kernel_launch(void* const* d_in, const int* in_sizes, int n_in,
                              void* d_out, int out_size, void* d_ws, size_t ws_size,
                              hipStream_t stream) {
    const float* x     = (const float*)d_in[0];
    const float* ctx   = (const float*)d_in[1];
    const float* wqkv  = (const float*)d_in[2];
    const float* wproj = (const float*)d_in[3];
    const float* bias  = (const float*)d_in[4];
    float* out  = (float*)d_out;                 // [4,2048,1024]
    float* attn = out + 8388608;                 // [4,16,1024,1024]
    float* qkv  = (float*)d_ws;                  // [8192,3072] f32 = 100.7 MB
    float* orr  = qkv + 25165824;                // [8192,1024] f32 = 33.6 MB (128 MiB total ws)
    // stats stashed in the out region (4 MB), consumed by k3, overwritten by k4
    float* statsM = out;                         // [64*8*1024]
    float* statsL = out + 524288;                // [64*8*1024]

    k1_qkv <<<dim3(24, 64),   256, 0, stream>>>(x, ctx, wqkv, qkv);
    k2_qkt <<<dim3(8, 8, 64), 256, 0, stream>>>(qkv, attn, statsM, statsL);
    k3_smpv<<<dim3(16, 64),   256, 0, stream>>>(qkv, attn, statsM, statsL, orr);
    k4_out <<<dim3(8, 64),    256, 0, stream>>>(orr, wproj, bias, out);
}

// Round 3
// 496.395 us; speedup vs baseline: 1.3716x; 1.2112x over previous
//
#include <hip/hip_runtime.h>
#include <stdint.h>

typedef short bf16x8 __attribute__((ext_vector_type(8)));
typedef unsigned short us8 __attribute__((ext_vector_type(8)));
typedef float f32x4 __attribute__((ext_vector_type(4)));
typedef unsigned short u16;
typedef unsigned int u32;

#define LDK 40   // padded LDS stride for k3 reg-staged tiles

__device__ __forceinline__ u16 f2bf(float f) {
    u32 u = __float_as_uint(f);
    u32 r = (u + 0x7FFFu + ((u >> 16) & 1u)) >> 16;   // RNE
    return (u16)r;
}
__device__ __forceinline__ float bf2f(u16 h) {
    return __uint_as_float(((u32)h) << 16);
}

typedef __attribute__((address_space(3))) unsigned int lds_uint;
typedef const __attribute__((address_space(1))) unsigned int glb_uint;
__device__ __forceinline__ void gld16(const void* g, void* l) {
    __builtin_amdgcn_global_load_lds((glb_uint*)g, (lds_uint*)l, 16, 0, 0);
}

// stage a 128x32 u16 tile (row stride in elems) into linear LDS [128][32] via global_load_lds.
// 8 wave-issues of 1KB each (16 rows x 64B); lane l -> row l/4, 16B chunk l%4.
__device__ __forceinline__ void gld_plane(const u16* __restrict__ g, int64_t strideElems,
                                          u16* lds, int w, int lane) {
#pragma unroll
    for (int i = 0; i < 2; ++i) {
        const int grp = w * 2 + i;                     // 0..7 -> rows grp*16..+15
        const u16* gp = g + (int64_t)(grp * 16 + (lane >> 2)) * strideElems + ((lane & 3) << 3);
        gld16(gp, &lds[grp * 512]);
    }
}

// split-3 MFMA step on linear [128][32] planes
__device__ __forceinline__ void mfma_step3_lin(const u16* Ah, const u16* Al,
                                               const u16* Bh, const u16* Bl,
                                               int wrow, int wcol, int lane,
                                               f32x4 acc[4][4]) {
    const int rl = lane & 15;
    const int k8 = (lane >> 4) << 3;
    bf16x8 ah[4], al[4], bh[4], bl[4];
#pragma unroll
    for (int i = 0; i < 4; ++i) {
        const int ra = (wrow + i * 16 + rl) * 32 + k8;
        const int rb = (wcol + i * 16 + rl) * 32 + k8;
        ah[i] = *reinterpret_cast<const bf16x8*>(&Ah[ra]);
        al[i] = *reinterpret_cast<const bf16x8*>(&Al[ra]);
        bh[i] = *reinterpret_cast<const bf16x8*>(&Bh[rb]);
        bl[i] = *reinterpret_cast<const bf16x8*>(&Bl[rb]);
    }
#pragma unroll
    for (int m = 0; m < 4; ++m)
#pragma unroll
        for (int n = 0; n < 4; ++n) {
            f32x4 c = acc[m][n];
            c = __builtin_amdgcn_mfma_f32_16x16x32_bf16(ah[m], bh[n], c, 0, 0, 0);
            c = __builtin_amdgcn_mfma_f32_16x16x32_bf16(ah[m], bl[n], c, 0, 0, 0);
            c = __builtin_amdgcn_mfma_f32_16x16x32_bf16(al[m], bh[n], c, 0, 0, 0);
            acc[m][n] = c;
        }
}

// ---------------- K0: f32 -> bf16 hi/lo plane conversion
// mode 0: row->row ; mode 1: x rows b*1024+s -> b*2048+s ; mode 2: ctx -> b*2048+1024+s
__global__ void k0_cvt(const float* __restrict__ src, u16* __restrict__ dh,
                       u16* __restrict__ dl, int mode) {
    const int64_t base = ((int64_t)blockIdx.x * 256 + threadIdx.x) * 8;
    const int row = (int)(base >> 10), col = (int)(base & 1023);
    int orow = row;
    if (mode == 1) orow = row + ((row >> 10) << 10);
    else if (mode == 2) orow = row + (((row >> 10) + 1) << 10);
    const float4* sp = reinterpret_cast<const float4*>(src + base);
    float4 a = sp[0], b = sp[1];
    float v[8] = {a.x, a.y, a.z, a.w, b.x, b.y, b.z, b.w};
    us8 hh, ll;
#pragma unroll
    for (int j = 0; j < 8; ++j) {
        u16 h = f2bf(v[j]);
        hh[j] = h;
        ll[j] = f2bf(v[j] - bf2f(h));
    }
    const int64_t o = (int64_t)orow * 1024 + col;
    *reinterpret_cast<us8*>(&dh[o]) = hh;
    if (dl) *reinterpret_cast<us8*>(&dl[o]) = ll;
}

// ---------------- K1: qkv = xc @ w_qkv^T  (split-3, gload_lds) -> bf16 hi/lo planes
__global__ __launch_bounds__(256, 2) void k1_qkv(const u16* __restrict__ Xh,
                                                 const u16* __restrict__ Xl,
                                                 const u16* __restrict__ Wh,
                                                 const u16* __restrict__ Wl,
                                                 u16* __restrict__ Qh,
                                                 u16* __restrict__ Ql) {
    __shared__ u16 LAh[4096], LAl[4096], LBh[4096], LBl[4096];
    const int tid = threadIdx.x, lane = tid & 63, w = tid >> 6;
    const int wrow = (w >> 1) << 6, wcol = (w & 1) << 6;
    const int n0 = blockIdx.x << 7, m0 = blockIdx.y << 7;
    const u16* Abh = Xh + (int64_t)m0 * 1024;
    const u16* Abl = Xl + (int64_t)m0 * 1024;
    const u16* Bbh = Wh + (int64_t)n0 * 1024;
    const u16* Bbl = Wl + (int64_t)n0 * 1024;
    f32x4 acc[4][4] = {};
    for (int kb = 0; kb < 32; ++kb) {
        const int k0 = kb * 32;
        gld_plane(Abh + k0, 1024, LAh, w, lane);
        gld_plane(Abl + k0, 1024, LAl, w, lane);
        gld_plane(Bbh + k0, 1024, LBh, w, lane);
        gld_plane(Bbl + k0, 1024, LBl, w, lane);
        __syncthreads();
        mfma_step3_lin(LAh, LAl, LBh, LBl, wrow, wcol, lane, acc);
        __syncthreads();
    }
    const int r4 = (lane >> 4) << 2, cc = lane & 15;
#pragma unroll
    for (int m = 0; m < 4; ++m)
#pragma unroll
        for (int n = 0; n < 4; ++n)
#pragma unroll
            for (int j = 0; j < 4; ++j) {
                const float v = acc[m][n][j];
                const u16 h = f2bf(v);
                const int64_t idx = (int64_t)(m0 + wrow + m * 16 + r4 + j) * 3072
                                    + (n0 + wcol + n * 16 + cc);
                Qh[idx] = h;
                Ql[idx] = f2bf(v - bf2f(h));
            }
}

// ---------------- K2: S = scale*QK^T -> attn region (pre-softmax) + per-tile stats
__global__ __launch_bounds__(256, 2) void k2_qkt(const u16* __restrict__ Qh,
                                                 const u16* __restrict__ Ql,
                                                 float* __restrict__ S,
                                                 float* __restrict__ statsM,
                                                 float* __restrict__ statsL) {
    __shared__ u16 LAh[4096], LAl[4096], LBh[4096], LBl[4096];
    __shared__ float pM[4][64], pL[4][64], rowMx[128];
    const int tid = threadIdx.x, lane = tid & 63, w = tid >> 6;
    const int wrow = (w >> 1) << 6, wcol = (w & 1) << 6;
    const int z = blockIdx.z, b = z >> 4, h = z & 15;
    const int n0 = blockIdx.x << 7, m0 = blockIdx.y << 7;
    // Q[i,e] = qkv[row 2i][h*128+e]
    const u16* Abh = Qh + ((int64_t)b * 2048 + 2 * m0) * 3072 + h * 128;
    const u16* Abl = Ql + ((int64_t)b * 2048 + 2 * m0) * 3072 + h * 128;
    // K[j,e] = qkv[row 2j+pk][c0k+e]
    const int pk  = (h < 8) ? 0 : 1;
    const int c0k = (h < 8) ? (2048 + h * 128) : ((h - 8) * 128);
    const u16* Bbh = Qh + ((int64_t)b * 2048 + 2 * n0 + pk) * 3072 + c0k;
    const u16* Bbl = Ql + ((int64_t)b * 2048 + 2 * n0 + pk) * 3072 + c0k;
    f32x4 acc[4][4] = {};
    for (int kb = 0; kb < 4; ++kb) {
        const int k0 = kb * 32;
        gld_plane(Abh + k0, 6144, LAh, w, lane);
        gld_plane(Abl + k0, 6144, LAl, w, lane);
        gld_plane(Bbh + k0, 6144, LBh, w, lane);
        gld_plane(Bbl + k0, 6144, LBl, w, lane);
        __syncthreads();
        mfma_step3_lin(LAh, LAl, LBh, LBl, wrow, wcol, lane, acc);
        __syncthreads();
    }
    float* Sout = S + ((int64_t)z << 20);
    const int r4 = (lane >> 4) << 2, cc = lane & 15;
#pragma unroll
    for (int m = 0; m < 4; ++m)
#pragma unroll
        for (int n = 0; n < 4; ++n)
#pragma unroll
            for (int j = 0; j < 4; ++j)
                Sout[(int64_t)(m0 + wrow + m * 16 + r4 + j) * 1024
                     + (n0 + wcol + n * 16 + cc)] = acc[m][n][j] * 0.125f;
    // ---- tile row stats (unscaled acc; scale folded into exp / final M)
    const int g = lane >> 4, rl = lane & 15;
#pragma unroll
    for (int m = 0; m < 4; ++m)
#pragma unroll
        for (int j = 0; j < 4; ++j) {
            float t = fmaxf(fmaxf(acc[m][0][j], acc[m][1][j]),
                            fmaxf(acc[m][2][j], acc[m][3][j]));
            t = fmaxf(t, __shfl_xor(t, 1));
            t = fmaxf(t, __shfl_xor(t, 2));
            t = fmaxf(t, __shfl_xor(t, 4));
            t = fmaxf(t, __shfl_xor(t, 8));
            if (rl == 0) pM[w][m * 16 + g * 4 + j] = t;
        }
    __syncthreads();
    if (tid < 128) {
        const int rh = tid >> 6;
        rowMx[tid] = fmaxf(pM[rh * 2][tid & 63], pM[rh * 2 + 1][tid & 63]);
    }
    __syncthreads();
#pragma unroll
    for (int m = 0; m < 4; ++m)
#pragma unroll
        for (int j = 0; j < 4; ++j) {
            const float M = rowMx[wrow + m * 16 + g * 4 + j];
            float s = 0.f;
#pragma unroll
            for (int n = 0; n < 4; ++n)
                s += __expf((acc[m][n][j] - M) * 0.125f);
            s += __shfl_xor(s, 1);
            s += __shfl_xor(s, 2);
            s += __shfl_xor(s, 4);
            s += __shfl_xor(s, 8);
            if (rl == 0) pL[w][m * 16 + g * 4 + j] = s;
        }
    __syncthreads();
    if (tid < 128) {
        const int rh = tid >> 6;
        const float l = pL[rh * 2][tid & 63] + pL[rh * 2 + 1][tid & 63];
        const int64_t idx = ((int64_t)(z * 8 + blockIdx.x) << 10) + m0 + tid;
        statsM[idx] = rowMx[tid] * 0.125f;
        statsL[idx] = l;
    }
}

// ---------------- K3: normalize S -> attn (single read) + O = P V -> Obf (bf16)
__global__ __launch_bounds__(256, 4) void k3_smpv(const u16* __restrict__ Qh,
                                                  float* __restrict__ S,
                                                  const float* __restrict__ statsM,
                                                  const float* __restrict__ statsL,
                                                  u16* __restrict__ Obf) {
    __shared__ u16 Ph[64 * LDK], Vh[128 * LDK];
    __shared__ float rowM[64], rowInv[64];
    const int tid = threadIdx.x;
    const int z = blockIdx.y, b = z >> 4, h = z & 15;
    const int m0 = blockIdx.x << 6;          // 64 q-rows per block
    if (tid < 64) {
        const int rr = m0 + tid;
        float Mt[8], Lt[8];
        float M = -3.0e38f;
#pragma unroll
        for (int t = 0; t < 8; ++t) {
            Mt[t] = statsM[((int64_t)(z * 8 + t) << 10) + rr];
            Lt[t] = statsL[((int64_t)(z * 8 + t) << 10) + rr];
            M = fmaxf(M, Mt[t]);
        }
        float l = 0.f;
#pragma unroll
        for (int t = 0; t < 8; ++t) l += Lt[t] * __expf(Mt[t] - M);
        rowM[tid] = M;
        rowInv[tid] = 1.0f / l;
    }
    __syncthreads();
    float* Sbase = S + ((int64_t)z << 20) + (int64_t)m0 * 1024;
    const int c0v = (h < 8) ? (1024 + h * 128) : (2048 + (h - 8) * 128);
    const u16* Vbase = Qh + ((int64_t)b * 2048 + 1) * 3072 + c0v;
    const int lane = tid & 63, w = tid >> 6;
    const int wrow = (w >> 1) << 5, wcol = (w & 1) << 6;   // wave tile 32q x 64e
    const int q = tid >> 2, c0 = (tid & 3) << 3;
    float* sp_base = Sbase + (int64_t)q * 1024 + c0;
    const float M = rowM[q], inv = rowInv[q];
    const int kk = tid & 31, e0 = (tid >> 5) << 4;
    f32x4 acc[2][4] = {};
    float4 ca = reinterpret_cast<const float4*>(sp_base)[0];
    float4 cb = reinterpret_cast<const float4*>(sp_base)[1];
    for (int kb = 0; kb < 32; ++kb) {
        float4 na, nb;
        if (kb < 31) {
            na = reinterpret_cast<const float4*>(sp_base + (kb + 1) * 32)[0];
            nb = reinterpret_cast<const float4*>(sp_base + (kb + 1) * 32)[1];
        }
        { // stage V (bf16 plane), transposed: Vh[e][kk]
            const u16* vp = Vbase + (int64_t)(kb * 32 + kk) * 6144 + e0;
            us8 v0 = *reinterpret_cast<const us8*>(vp);
            us8 v1 = *reinterpret_cast<const us8*>(vp + 8);
#pragma unroll
            for (int j = 0; j < 8; ++j) {
                Vh[(e0 + j) * LDK + kk] = v0[j];
                Vh[(e0 + 8 + j) * LDK + kk] = v1[j];
            }
        }
        { // normalize P, write final attn, stage Ph
            float p[8] = {ca.x,ca.y,ca.z,ca.w, cb.x,cb.y,cb.z,cb.w};
            us8 hh;
#pragma unroll
            for (int j = 0; j < 8; ++j) {
                const float e = __expf(p[j] - M) * inv;
                p[j] = e;
                hh[j] = f2bf(e);
            }
            float4* st = reinterpret_cast<float4*>(sp_base + kb * 32);
            st[0] = make_float4(p[0], p[1], p[2], p[3]);
            st[1] = make_float4(p[4], p[5], p[6], p[7]);
            *reinterpret_cast<us8*>(&Ph[q * LDK + c0]) = hh;
        }
        __syncthreads();
        { // PV mfma (hi-only)
            const int rl = lane & 15, k8 = (lane >> 4) << 3;
            bf16x8 a[2], bv[4];
#pragma unroll
            for (int i = 0; i < 2; ++i)
                a[i] = *reinterpret_cast<const bf16x8*>(&Ph[(wrow + i * 16 + rl) * LDK + k8]);
#pragma unroll
            for (int i = 0; i < 4; ++i)
                bv[i] = *reinterpret_cast<const bf16x8*>(&Vh[(wcol + i * 16 + rl) * LDK + k8]);
#pragma unroll
            for (int m = 0; m < 2; ++m)
#pragma unroll
                for (int n = 0; n < 4; ++n)
                    acc[m][n] = __builtin_amdgcn_mfma_f32_16x16x32_bf16(a[m], bv[n], acc[m][n], 0, 0, 0);
        }
        __syncthreads();
        if (kb < 31) { ca = na; cb = nb; }
    }
    // scatter O[i,e] -> o_r[b, 2i+(h>>3), (h&7)*128+e]  as bf16
    const int r4 = (lane >> 4) << 2, cc = lane & 15;
    const int po = h >> 3, cb2 = (h & 7) << 7;
#pragma unroll
    for (int m = 0; m < 2; ++m)
#pragma unroll
        for (int n = 0; n < 4; ++n)
#pragma unroll
            for (int j = 0; j < 4; ++j) {
                const int qrow = m0 + wrow + m * 16 + r4 + j;
                Obf[((int64_t)b * 2048 + 2 * qrow + po) * 1024
                    + cb2 + wcol + n * 16 + cc] = f2bf(acc[m][n][j]);
            }
}

// ---------------- K4: out = o @ w_proj^T + b_proj   (hi-only bf16, gload_lds)
__global__ __launch_bounds__(256, 3) void k4_out(const u16* __restrict__ Obf,
                                                 const u16* __restrict__ Ph,
                                                 const float* __restrict__ bias,
                                                 float* __restrict__ out) {
    __shared__ u16 LA[4096], LB[4096];
    const int tid = threadIdx.x, lane = tid & 63, w = tid >> 6;
    const int wrow = (w >> 1) << 6, wcol = (w & 1) << 6;
    const int n0 = blockIdx.x << 7, m0 = blockIdx.y << 7;
    const u16* Ab = Obf + (int64_t)m0 * 1024;
    const u16* Bb = Ph + (int64_t)n0 * 1024;
    f32x4 acc[4][4] = {};
    const int rl = lane & 15, k8 = (lane >> 4) << 3;
    for (int kb = 0; kb < 32; ++kb) {
        const int k0 = kb * 32;
        gld_plane(Ab + k0, 1024, LA, w, lane);
        gld_plane(Bb + k0, 1024, LB, w, lane);
        __syncthreads();
        bf16x8 a[4], bv[4];
#pragma unroll
        for (int i = 0; i < 4; ++i) {
            a[i]  = *reinterpret_cast<const bf16x8*>(&LA[(wrow + i * 16 + rl) * 32 + k8]);
            bv[i] = *reinterpret_cast<const bf16x8*>(&LB[(wcol + i * 16 + rl) * 32 + k8]);
        }
#pragma unroll
        for (int m = 0; m < 4; ++m)
#pragma unroll
            for (int n = 0; n < 4; ++n)
                acc[m][n] = __builtin_amdgcn_mfma_f32_16x16x32_bf16(a[m], bv[n], acc[m][n], 0, 0, 0);
        __syncthreads();
    }
    const int r4 = (lane >> 4) << 2, cc = lane & 15;
#pragma unroll
    for (int m = 0; m < 4; ++m)
#pragma unroll
        for (int n = 0; n < 4; ++n)
#pragma unroll
            for (int j = 0; j < 4; ++j)
                out[(int64_t)(m0 + wrow + m * 16 + r4 + j) * 1024
                    + (n0 + wcol + n * 16 + cc)]
                    = acc[m][n][j] + bias[n0 + wcol + n * 16 + cc];
}

extern "C" void kernel_launch(void* const* d_in, const int* in_sizes, int n_in,
                              void* d_out, int out_size, void* d_ws, size_t ws_size,
                              hipStream_t stream) {
    const float* x     = (const float*)d_in[0];
    const float* ctx   = (const float*)d_in[1];
    const float* wqkv  = (const float*)d_in[2];
    const float* wproj = (const float*)d_in[3];
    const float* bias  = (const float*)d_in[4];
    float* out  = (float*)d_out;                 // [4,2048,1024]
    float* attn = out + 8388608;                 // [4,16,1024,1024] f32 (268 MB)

    // ws layout (bf16 planes), total 132.1 MB
    u16* QKVh = (u16*)d_ws;                      // [8192,3072]
    u16* QKVl = QKVh + 25165824;                 // [8192,3072]
    u16* Wh   = QKVl + 25165824;                 // [3072,1024]
    u16* Wl   = Wh + 3145728;
    u16* Phw  = Wl + 3145728;                    // w_proj hi [1024,1024]
    u16* Obf  = Phw + 1048576;                   // o bf16 [8192,1024]

    // X planes live in the attn region (clobbered by k2's S write, after k1 is done)
    u16* Xh = (u16*)attn;                        // [8192,1024]
    u16* Xl = Xh + 8388608;

    // stats in the out region (consumed by k3, overwritten by k4)
    float* statsM = out;                         // [64*8*1024]
    float* statsL = out + 524288;

    k0_cvt<<<dim3(1536), 256, 0, stream>>>(wqkv,  Wh, Wl, 0);
    k0_cvt<<<dim3(2048), 256, 0, stream>>>(x,     Xh, Xl, 1);
    k0_cvt<<<dim3(2048), 256, 0, stream>>>(ctx,   Xh, Xl, 2);
    k0_cvt<<<dim3(512),  256, 0, stream>>>(wproj, Phw, (u16*)nullptr, 0);

    k1_qkv <<<dim3(24, 64),   256, 0, stream>>>(Xh, Xl, Wh, Wl, QKVh, QKVl);
    k2_qkt <<<dim3(8, 8, 64), 256, 0, stream>>>(QKVh, QKVl, attn, statsM, statsL);
    k3_smpv<<<dim3(16, 64),   256, 0, stream>>>(QKVh, attn, statsM, statsL, Obf);
    k4_out <<<dim3(8, 64),    256, 0, stream>>>(Obf, Phw, bias, out);
}

// Round 4
// 299.252 us; speedup vs baseline: 2.2751x; 1.6588x over previous
//
#include <hip/hip_runtime.h>
#include <stdint.h>

typedef short bf16x8 __attribute__((ext_vector_type(8)));
typedef unsigned short us8 __attribute__((ext_vector_type(8)));
typedef float f32x4 __attribute__((ext_vector_type(4)));
typedef unsigned short u16;
typedef unsigned int u32;

__device__ __forceinline__ u16 f2bf(float f) {
    u32 u = __float_as_uint(f);
    return (u16)((u + 0x7FFFu + ((u >> 16) & 1u)) >> 16);   // RNE
}
__device__ __forceinline__ float bf2f(u16 h) { return __uint_as_float(((u32)h) << 16); }

typedef __attribute__((address_space(3))) unsigned int lds_uint;
typedef const __attribute__((address_space(1))) unsigned int glb_uint;
__device__ __forceinline__ void gld16(const void* g, void* l) {
    __builtin_amdgcn_global_load_lds((glb_uint*)g, (lds_uint*)l, 16, 0, 0);
}

// ---- swizzled staging (rule #21: linear LDS dest + pre-swizzled per-lane global
//      source + matching XOR on the ds_read side) ----

// [128 rows][32 cols] bf16 tile; 2-bit granule swizzle slot = g ^ ((row>>1)&3)
__device__ __forceinline__ void gld_p128x32(const u16* __restrict__ g, int64_t stride,
                                            u16* lds, int w, int lane) {
#pragma unroll
    for (int i = 0; i < 2; ++i) {
        const int grp = w * 2 + i;
        const int row = grp * 16 + (lane >> 2);
        const int sl = (lane & 3) ^ ((row >> 1) & 3);
        gld16(g + (int64_t)row * stride + (sl << 3), &lds[grp * 512]);
    }
}
__device__ __forceinline__ int idx128x32(int row, int gk) {
    return row * 32 + ((gk ^ ((row >> 1) & 3)) << 3);
}

// [32 rows][128 cols] bf16 tile; 3-bit granule swizzle slot = g ^ (row&7)
__device__ __forceinline__ void gld_t32x128(const u16* __restrict__ g, int64_t stride,
                                            u16* lds, int w, int lane) {
#pragma unroll
    for (int i = 0; i < 2; ++i) {
        const int gg = w * 2 + i;
        const int row = gg * 4 + (lane >> 4);
        const int gs = (lane & 15) ^ (row & 7);
        gld16(g + (int64_t)row * stride + (gs << 3), &lds[gg * 512]);
    }
}
__device__ __forceinline__ int idx32x128(int row, int gk) {
    return row * 128 + ((gk ^ (row & 7)) << 3);
}

// hi-only MFMA step on two swizzled [128][32] planes (4 waves, 64x64 per wave)
__device__ __forceinline__ void mfma_step1(const u16* LA, const u16* LB,
                                           int wrow, int wcol, int lane,
                                           f32x4 acc[4][4]) {
    const int rl = lane & 15, gk = lane >> 4;
    bf16x8 a[4], bv[4];
#pragma unroll
    for (int i = 0; i < 4; ++i) {
        a[i]  = *reinterpret_cast<const bf16x8*>(&LA[idx128x32(wrow + i * 16 + rl, gk)]);
        bv[i] = *reinterpret_cast<const bf16x8*>(&LB[idx128x32(wcol + i * 16 + rl, gk)]);
    }
#pragma unroll
    for (int m = 0; m < 4; ++m)
#pragma unroll
        for (int n = 0; n < 4; ++n)
            acc[m][n] = __builtin_amdgcn_mfma_f32_16x16x32_bf16(a[m], bv[n], acc[m][n], 0, 0, 0);
}

// ---------------- K0: f32 -> bf16 (hi only) plane conversion
// mode 0: row->row ; mode 1: x rows b*1024+s -> b*2048+s ; mode 2: ctx -> b*2048+1024+s
__global__ void k0_cvt(const float* __restrict__ src, u16* __restrict__ dh, int mode) {
    const int64_t base = ((int64_t)blockIdx.x * 256 + threadIdx.x) * 8;
    const int row = (int)(base >> 10), col = (int)(base & 1023);
    int orow = row;
    if (mode == 1) orow = row + ((row >> 10) << 10);
    else if (mode == 2) orow = row + (((row >> 10) + 1) << 10);
    const float4* sp = reinterpret_cast<const float4*>(src + base);
    float4 a = sp[0], b = sp[1];
    float v[8] = {a.x, a.y, a.z, a.w, b.x, b.y, b.z, b.w};
    us8 hh;
#pragma unroll
    for (int j = 0; j < 8; ++j) hh[j] = f2bf(v[j]);
    *reinterpret_cast<us8*>(&dh[(int64_t)orow * 1024 + col]) = hh;
}

// ---------------- K1: qkv = xc @ w_qkv^T  (hi-only bf16) -> Qh
__global__ __launch_bounds__(256, 2) void k1_qkv(const u16* __restrict__ Xh,
                                                 const u16* __restrict__ Wh,
                                                 u16* __restrict__ Qh) {
    __shared__ u16 LA[4096], LB[4096];
    const int tid = threadIdx.x, lane = tid & 63, w = tid >> 6;
    const int wrow = (w >> 1) << 6, wcol = (w & 1) << 6;
    const int n0 = blockIdx.x << 7, m0 = blockIdx.y << 7;
    const u16* Ab = Xh + (int64_t)m0 * 1024;
    const u16* Bb = Wh + (int64_t)n0 * 1024;
    f32x4 acc[4][4] = {};
    for (int kb = 0; kb < 32; ++kb) {
        gld_p128x32(Ab + kb * 32, 1024, LA, w, lane);
        gld_p128x32(Bb + kb * 32, 1024, LB, w, lane);
        __syncthreads();
        mfma_step1(LA, LB, wrow, wcol, lane, acc);
        __syncthreads();
    }
    const int r4 = (lane >> 4) << 2, cc = lane & 15;
#pragma unroll
    for (int m = 0; m < 4; ++m)
#pragma unroll
        for (int n = 0; n < 4; ++n)
#pragma unroll
            for (int j = 0; j < 4; ++j)
                Qh[(int64_t)(m0 + wrow + m * 16 + r4 + j) * 3072
                   + (n0 + wcol + n * 16 + cc)] = f2bf(acc[m][n][j]);
}

// ---------------- K0v: pre-transpose V planes: Vt[z][e 128][kpos 1024]
__global__ __launch_bounds__(256, 2) void k0v_vt(const u16* __restrict__ Qh,
                                                 u16* __restrict__ Vt) {
    __shared__ u16 T[128][144];
    const int tid = threadIdx.x;
    const int z = blockIdx.y, b = z >> 4, h = z & 15;
    const int kt = blockIdx.x;                       // 128-kpos tile
    const int c0v = (h < 8) ? (1024 + h * 128) : (2048 + (h - 8) * 128);
    const u16* Vbase = Qh + ((int64_t)b * 2048 + 1) * 3072 + c0v;
    const int row = tid >> 1, e0 = (tid & 1) << 6;   // V row (kpos), 64 e's
    const u16* src = Vbase + (int64_t)(kt * 128 + row) * 6144 + e0;
#pragma unroll
    for (int i = 0; i < 8; ++i) {
        us8 v = *reinterpret_cast<const us8*>(src + i * 8);
#pragma unroll
        for (int j = 0; j < 8; ++j) T[e0 + i * 8 + j][row] = v[j];
    }
    __syncthreads();
    const int e = tid >> 1, k0 = (tid & 1) << 6;
    u16* dst = Vt + ((int64_t)z << 17) + (int64_t)e * 1024 + kt * 128 + k0;
#pragma unroll
    for (int i = 0; i < 8; ++i)
        *reinterpret_cast<us8*>(dst + i * 8) = *reinterpret_cast<const us8*>(&T[e][k0 + i * 8]);
}

// ---------------- K2: stats-only QK^T: per-128x128-tile row (max, sumexp)
__global__ __launch_bounds__(256, 2) void k2_stats(const u16* __restrict__ Qh,
                                                   float* __restrict__ statsM,
                                                   float* __restrict__ statsL) {
    __shared__ u16 LA[4096], LB[4096];
    __shared__ float pM[4][64], pL[4][64], rowMx[128];
    const int tid = threadIdx.x, lane = tid & 63, w = tid >> 6;
    const int wrow = (w >> 1) << 6, wcol = (w & 1) << 6;
    const int z = blockIdx.z, b = z >> 4, h = z & 15;
    const int n0 = blockIdx.x << 7, m0 = blockIdx.y << 7;
    const u16* Ab = Qh + ((int64_t)b * 2048 + 2 * m0) * 3072 + h * 128;
    const int pk  = (h < 8) ? 0 : 1;
    const int c0k = (h < 8) ? (2048 + h * 128) : ((h - 8) * 128);
    const u16* Bb = Qh + ((int64_t)b * 2048 + 2 * n0 + pk) * 3072 + c0k;
    f32x4 acc[4][4] = {};
    for (int kb = 0; kb < 4; ++kb) {
        gld_p128x32(Ab + kb * 32, 6144, LA, w, lane);
        gld_p128x32(Bb + kb * 32, 6144, LB, w, lane);
        __syncthreads();
        mfma_step1(LA, LB, wrow, wcol, lane, acc);
        __syncthreads();
    }
    const int g = lane >> 4, rl = lane & 15;
#pragma unroll
    for (int m = 0; m < 4; ++m)
#pragma unroll
        for (int j = 0; j < 4; ++j) {
            float t = fmaxf(fmaxf(acc[m][0][j], acc[m][1][j]),
                            fmaxf(acc[m][2][j], acc[m][3][j]));
            t = fmaxf(t, __shfl_xor(t, 1));
            t = fmaxf(t, __shfl_xor(t, 2));
            t = fmaxf(t, __shfl_xor(t, 4));
            t = fmaxf(t, __shfl_xor(t, 8));
            if (rl == 0) pM[w][m * 16 + g * 4 + j] = t;
        }
    __syncthreads();
    if (tid < 128) {
        const int rh = tid >> 6;
        rowMx[tid] = fmaxf(pM[rh * 2][tid & 63], pM[rh * 2 + 1][tid & 63]);
    }
    __syncthreads();
#pragma unroll
    for (int m = 0; m < 4; ++m)
#pragma unroll
        for (int j = 0; j < 4; ++j) {
            const float M = rowMx[wrow + m * 16 + g * 4 + j];
            float s = 0.f;
#pragma unroll
            for (int n = 0; n < 4; ++n)
                s += __expf((acc[m][n][j] - M) * 0.125f);
            s += __shfl_xor(s, 1);
            s += __shfl_xor(s, 2);
            s += __shfl_xor(s, 4);
            s += __shfl_xor(s, 8);
            if (rl == 0) pL[w][m * 16 + g * 4 + j] = s;
        }
    __syncthreads();
    if (tid < 128) {
        const int rh = tid >> 6;
        const float l = pL[rh * 2][tid & 63] + pL[rh * 2 + 1][tid & 63];
        const int64_t idx = ((int64_t)(z * 8 + blockIdx.x) << 10) + m0 + tid;
        statsM[idx] = rowMx[tid] * 0.125f;
        statsL[idx] = l;
    }
}

// ---------------- K3: fused recompute-QK^T + softmax -> attn f32 + PV -> Obf
__global__ __launch_bounds__(256, 4) void k3_fused(const u16* __restrict__ Qh,
                                                   const u16* __restrict__ Vt,
                                                   const float* __restrict__ statsM,
                                                   const float* __restrict__ statsL,
                                                   float* __restrict__ attn,
                                                   u16* __restrict__ Obf) {
    __shared__ u16 LQ[4096], LK[4096], LV[4096], Ph[32 * 40];
    __shared__ float rowM[32], rowInv[32];
    const int tid = threadIdx.x, lane = tid & 63, w = tid >> 6;
    const int z = blockIdx.y, b = z >> 4, h = z & 15;
    const int m0 = blockIdx.x << 5;                  // 32 q-rows per block
    const u16* Qbase = Qh + ((int64_t)b * 2048 + 2 * m0) * 3072 + h * 128;
    gld_t32x128(Qbase, 6144, LQ, w, lane);           // Q tile staged once
    if (tid < 32) {
        const int rr = m0 + tid;
        float Mt[8], Lt[8], M = -3.0e38f;
#pragma unroll
        for (int t = 0; t < 8; ++t) {
            Mt[t] = statsM[((int64_t)(z * 8 + t) << 10) + rr];
            Lt[t] = statsL[((int64_t)(z * 8 + t) << 10) + rr];
            M = fmaxf(M, Mt[t]);
        }
        float l = 0.f;
#pragma unroll
        for (int t = 0; t < 8; ++t) l += Lt[t] * __expf(Mt[t] - M);
        rowM[tid] = M;
        rowInv[tid] = 1.0f / l;
    }
    const int pk  = (h < 8) ? 0 : 1;
    const int c0k = (h < 8) ? (2048 + h * 128) : ((h - 8) * 128);
    const u16* Kbase = Qh + ((int64_t)b * 2048 + pk) * 3072 + c0k;
    const u16* Vtz = Vt + ((int64_t)z << 17);
    float* attnZ = attn + ((int64_t)z << 20);
    const int sm = w & 1, sn = w >> 1;               // S-tile of this wave
    const int rl = lane & 15, gk = lane >> 4;
    const int r4 = gk << 2, cc = rl;
    f32x4 po[4] = {};                                // PV acc: rows sm*16.., cols sn*64..
    for (int c = 0; c < 32; ++c) {
        __syncthreads();                             // prior chunk's readers done
        gld_t32x128(Kbase + (int64_t)c * 32 * 6144, 6144, LK, w, lane);
        gld_p128x32(Vtz + c * 32, 1024, LV, w, lane);
        __syncthreads();                             // LK/LV (and LQ) resident
        f32x4 s = {};
#pragma unroll
        for (int ks = 0; ks < 4; ++ks) {
            bf16x8 a  = *reinterpret_cast<const bf16x8*>(&LQ[idx32x128(sm * 16 + rl, ks * 4 + gk)]);
            bf16x8 bb = *reinterpret_cast<const bf16x8*>(&LK[idx32x128(sn * 16 + rl, ks * 4 + gk)]);
            s = __builtin_amdgcn_mfma_f32_16x16x32_bf16(a, bb, s, 0, 0, 0);
        }
#pragma unroll
        for (int j = 0; j < 4; ++j) {
            const int q = sm * 16 + r4 + j;
            const float p = __expf(s[j] * 0.125f - rowM[q]) * rowInv[q];
            attnZ[(int64_t)(m0 + q) * 1024 + c * 32 + sn * 16 + cc] = p;
            Ph[q * 40 + sn * 16 + cc] = f2bf(p);
        }
        __syncthreads();                             // Ph visible
        bf16x8 pa = *reinterpret_cast<const bf16x8*>(&Ph[(sm * 16 + rl) * 40 + (gk << 3)]);
#pragma unroll
        for (int n = 0; n < 4; ++n) {
            bf16x8 bv = *reinterpret_cast<const bf16x8*>(&LV[idx128x32(sn * 64 + n * 16 + rl, gk)]);
            po[n] = __builtin_amdgcn_mfma_f32_16x16x32_bf16(pa, bv, po[n], 0, 0, 0);
        }
    }
    // scatter O[q,e] -> o_r[b, 2q+(h>>3), (h&7)*128+e]  as bf16
    const int poh = h >> 3, cb2 = (h & 7) << 7;
#pragma unroll
    for (int n = 0; n < 4; ++n)
#pragma unroll
        for (int j = 0; j < 4; ++j) {
            const int qrow = m0 + sm * 16 + r4 + j;
            Obf[((int64_t)b * 2048 + 2 * qrow + poh) * 1024
                + cb2 + sn * 64 + n * 16 + cc] = f2bf(po[n][j]);
        }
}

// ---------------- K4: out = o @ w_proj^T + b_proj  (hi-only bf16)
__global__ __launch_bounds__(256, 2) void k4_out(const u16* __restrict__ Obf,
                                                 const u16* __restrict__ Phw,
                                                 const float* __restrict__ bias,
                                                 float* __restrict__ out) {
    __shared__ u16 LA[4096], LB[4096];
    const int tid = threadIdx.x, lane = tid & 63, w = tid >> 6;
    const int wrow = (w >> 1) << 6, wcol = (w & 1) << 6;
    const int n0 = blockIdx.x << 7, m0 = blockIdx.y << 7;
    const u16* Ab = Obf + (int64_t)m0 * 1024;
    const u16* Bb = Phw + (int64_t)n0 * 1024;
    f32x4 acc[4][4] = {};
    for (int kb = 0; kb < 32; ++kb) {
        gld_p128x32(Ab + kb * 32, 1024, LA, w, lane);
        gld_p128x32(Bb + kb * 32, 1024, LB, w, lane);
        __syncthreads();
        mfma_step1(LA, LB, wrow, wcol, lane, acc);
        __syncthreads();
    }
    const int r4 = (lane >> 4) << 2, cc = lane & 15;
#pragma unroll
    for (int m = 0; m < 4; ++m)
#pragma unroll
        for (int n = 0; n < 4; ++n)
#pragma unroll
            for (int j = 0; j < 4; ++j)
                out[(int64_t)(m0 + wrow + m * 16 + r4 + j) * 1024
                    + (n0 + wcol + n * 16 + cc)]
                    = acc[m][n][j] + bias[n0 + wcol + n * 16 + cc];
}

extern "C" void kernel_launch(void* const* d_in, const int* in_sizes, int n_in,
                              void* d_out, int out_size, void* d_ws, size_t ws_size,
                              hipStream_t stream) {
    const float* x     = (const float*)d_in[0];
    const float* ctx   = (const float*)d_in[1];
    const float* wqkv  = (const float*)d_in[2];
    const float* wproj = (const float*)d_in[3];
    const float* bias  = (const float*)d_in[4];
    float* out  = (float*)d_out;                 // [4,2048,1024]
    float* attn = out + 8388608;                 // [4,16,1024,1024] f32

    // ws (u16), total 92.3 MB
    u16* Qh  = (u16*)d_ws;                       // [8192,3072]
    u16* Vt  = Qh + 25165824;                    // [64,128,1024]
    u16* Wh  = Vt + 8388608;                     // [3072,1024]
    u16* Phw = Wh + 3145728;                     // [1024,1024]
    u16* Obf = Phw + 1048576;                    // [8192,1024]

    // X bf16 plane parked in the attn region (dead once k1 finishes; k3 overwrites)
    u16* Xh = (u16*)attn;                        // [8192,1024]
    // stats parked in the out region (consumed by k3, overwritten by k4)
    float* statsM = out;                         // [64*8*1024]
    float* statsL = out + 524288;

    k0_cvt<<<dim3(1536), 256, 0, stream>>>(wqkv,  Wh,  0);
    k0_cvt<<<dim3(2048), 256, 0, stream>>>(x,     Xh,  1);
    k0_cvt<<<dim3(2048), 256, 0, stream>>>(ctx,   Xh,  2);
    k0_cvt<<<dim3(512),  256, 0, stream>>>(wproj, Phw, 0);

    k1_qkv  <<<dim3(24, 64),   256, 0, stream>>>(Xh, Wh, Qh);
    k0v_vt  <<<dim3(8, 64),    256, 0, stream>>>(Qh, Vt);
    k2_stats<<<dim3(8, 8, 64), 256, 0, stream>>>(Qh, statsM, statsL);
    k3_fused<<<dim3(32, 64),   256, 0, stream>>>(Qh, Vt, statsM, statsL, attn, Obf);
    k4_out  <<<dim3(8, 64),    256, 0, stream>>>(Obf, Phw, bias, out);
}